// Round 13
// baseline (144.928 us; speedup 1.0000x reference)
//
#include <hip/hip_runtime.h>

// TensorProductConv: Z[rows[e]] += msg(X[cols[e]], Y[e], W[e]),  msg is 352 f32.
// Inputs: X (N,128) f32, Y (E,4) f32, W (E,160) f32, rows (E) int32, cols (E) int32
// Output: Z (N, 352) f32.
//
// Pipeline: memset(cnt) -> scatter_bin (KCAP=64 bins, {e,col} i2 records,
// 4 edges/thread via int4, nontemporal slot writes) -> tpc_gather (one full
// 64-lane wave per node, even/odd slot split, __shfl_xor(32) combine, x2
// unroll per slot; overflowed nodes scan ovf_list themselves -- zero cost
// when no overflow).

#define SQRT3_INV 0.57735026918962576451f
#define SQRT2_INV 0.70710678118654752440f
#define KCAP 64

typedef __attribute__((ext_vector_type(4))) float f4;
typedef __attribute__((ext_vector_type(2))) int   i2;
typedef __attribute__((ext_vector_type(4))) int   i4;
struct F3 { float a, b, c; };   // 12 B -> global_load_dwordx3

#define EDGE_BODY(E_, C_)                                                     \
    do {                                                                      \
        const float* We = W + (size_t)(unsigned)(E_) * 160;                   \
        const float* Xr = X + (size_t)(unsigned)(C_) * 128;                   \
        const f4 yv = *reinterpret_cast<const f4*>(Y + (size_t)(unsigned)(E_) * 4); \
        const float x0 = Xr[u];                                               \
        const F3 x1 = *reinterpret_cast<const F3*>(Xr + 32 + 3 * u);          \
        const float x1a = x1.a, x1b = x1.b, x1c = x1.c;                       \
        const float y0 = yv.x, y1a = yv.y, y1b = yv.z, y1c = yv.w;            \
        const float w0 = __builtin_nontemporal_load(We + u);                  \
        const float w1 = __builtin_nontemporal_load(We + 32 + u);             \
        const float w2 = __builtin_nontemporal_load(We + 64 + u);             \
        const float w3 = __builtin_nontemporal_load(We + 96 + u);             \
        const float w4 = __builtin_nontemporal_load(We + 128 + u);            \
        a1 += w0 * x0 * y0;                                                   \
        const float w1x0 = w1 * x0;                                           \
        a2a += w1x0 * y1a; a2b += w1x0 * y1b; a2c += w1x0 * y1c;              \
        const float w2y0 = w2 * y0;                                           \
        a3a += w2y0 * x1a; a3b += w2y0 * x1b; a3c += w2y0 * x1c;              \
        const float dot = x1a * y1a + x1b * y1b + x1c * y1c;                  \
        a4 += w3 * dot * SQRT3_INV;                                           \
        const float w4s = w4 * SQRT2_INV;                                     \
        a5a += w4s * (x1b * y1c - x1c * y1b);                                 \
        a5b += w4s * (x1c * y1a - x1a * y1c);                                 \
        a5c += w4s * (x1a * y1b - x1b * y1a);                                 \
    } while (0)

__device__ __forceinline__ void bin_one(int e, int r, int c,
                                        int* __restrict__ cnt, i2* __restrict__ slots,
                                        int* __restrict__ ovf_list, int n_nodes) {
    int p = atomicAdd(&cnt[r], 1);
    if (p < KCAP) {
        i2 rec; rec.x = e; rec.y = c;
        __builtin_nontemporal_store(rec, &slots[(size_t)r * KCAP + p]);
    } else {
        int q = atomicAdd(&cnt[n_nodes], 1);
        ovf_list[q] = e;
    }
}

// ---------- build: bin edges by destination row, 4 edges per thread ----------
__global__ void scatter_bin_kernel(const int* __restrict__ rows, const int* __restrict__ cols,
                                   int* __restrict__ cnt, i2* __restrict__ slots,
                                   int* __restrict__ ovf_list, int n_nodes, int nE) {
    int t = blockIdx.x * blockDim.x + threadIdx.x;
    int e0 = t * 4;
    if (e0 >= nE) return;
    if (e0 + 3 < nE) {
        const i4 rr = *reinterpret_cast<const i4*>(rows + e0);
        const i4 cc = *reinterpret_cast<const i4*>(cols + e0);
        bin_one(e0 + 0, rr.x, cc.x, cnt, slots, ovf_list, n_nodes);
        bin_one(e0 + 1, rr.y, cc.y, cnt, slots, ovf_list, n_nodes);
        bin_one(e0 + 2, rr.z, cc.z, cnt, slots, ovf_list, n_nodes);
        bin_one(e0 + 3, rr.w, cc.w, cnt, slots, ovf_list, n_nodes);
    } else {
        for (int e = e0; e < nE; ++e)
            bin_one(e, rows[e], cols[e], cnt, slots, ovf_list, n_nodes);
    }
}

// ---------- main gather: one node per full 64-lane wave, slot-split ----------
__global__ __launch_bounds__(256) void tpc_gather(
    const float* __restrict__ X,
    const float* __restrict__ Y,
    const float* __restrict__ W,
    const int* __restrict__ rows,
    const int* __restrict__ cols,
    const i2* __restrict__ slots,
    const int* __restrict__ cnt,
    const int* __restrict__ ovf_list,
    float* __restrict__ Z,
    int n_nodes)
{
    int node = blockIdx.x * 4 + (threadIdx.x >> 6);   // 4 waves per 256-thr block
    if (node >= n_nodes) return;
    const int lane = threadIdx.x & 63;
    const int u    = lane & 31;     // channel
    const int slot = lane >> 5;     // 0: even edges, 1: odd edges

    float a1 = 0.f, a2a = 0.f, a2b = 0.f, a2c = 0.f;
    float a3a = 0.f, a3b = 0.f, a3c = 0.f, a4 = 0.f;
    float a5a = 0.f, a5b = 0.f, a5c = 0.f;

    const int ncnt = cnt[node];
    int n = ncnt > KCAP ? KCAP : ncnt;
    const i2* sb = slots + (size_t)node * KCAP;

    int i = 0;
    for (; i + 3 < n; i += 4) {
        const i2 ec0 = sb[i + slot];
        const i2 ec1 = sb[i + 2 + slot];
        EDGE_BODY(ec0.x, ec0.y);
        EDGE_BODY(ec1.x, ec1.y);
    }
    for (; i + slot < n; i += 2) {
        const i2 ec0 = sb[i + slot];
        EDGE_BODY(ec0.x, ec0.y);
    }

    // overflow (never in practice): owning wave handles its own edges,
    // race-free because it happens before this wave's single Z store.
    if (ncnt > KCAP) {
        const int tot = cnt[n_nodes];
        for (int j = slot; j < tot; j += 2) {
            const int e = ovf_list[j];
            if (rows[e] == node) {
                const int c = cols[e];
                EDGE_BODY(e, c);
            }
        }
    }

    // combine slot halves (lane <-> lane^32)
    a1  += __shfl_xor(a1,  32, 64);
    a2a += __shfl_xor(a2a, 32, 64);
    a2b += __shfl_xor(a2b, 32, 64);
    a2c += __shfl_xor(a2c, 32, 64);
    a3a += __shfl_xor(a3a, 32, 64);
    a3b += __shfl_xor(a3b, 32, 64);
    a3c += __shfl_xor(a3c, 32, 64);
    a4  += __shfl_xor(a4,  32, 64);
    a5a += __shfl_xor(a5a, 32, 64);
    a5b += __shfl_xor(a5b, 32, 64);
    a5c += __shfl_xor(a5c, 32, 64);

    if (slot == 0) {
        float* Zr = Z + (size_t)node * 352;
        __builtin_nontemporal_store(a1,  Zr + u);
        __builtin_nontemporal_store(a2a, Zr + 32 + 3 * u + 0);
        __builtin_nontemporal_store(a2b, Zr + 32 + 3 * u + 1);
        __builtin_nontemporal_store(a2c, Zr + 32 + 3 * u + 2);
        __builtin_nontemporal_store(a3a, Zr + 128 + 3 * u + 0);
        __builtin_nontemporal_store(a3b, Zr + 128 + 3 * u + 1);
        __builtin_nontemporal_store(a3c, Zr + 128 + 3 * u + 2);
        __builtin_nontemporal_store(a4,  Zr + 224 + u);
        __builtin_nontemporal_store(a5a, Zr + 256 + 3 * u + 0);
        __builtin_nontemporal_store(a5b, Zr + 256 + 3 * u + 1);
        __builtin_nontemporal_store(a5c, Zr + 256 + 3 * u + 2);
    }
}

// ---------- last-resort fallback (atomic scatter) if ws too small ----------
__global__ __launch_bounds__(256) void tpc_edge_kernel(
    const float* __restrict__ X, const float* __restrict__ Y, const float* __restrict__ W,
    const int* __restrict__ rows, const int* __restrict__ cols, float* __restrict__ Z, int n_edges)
{
    int gid = blockIdx.x * blockDim.x + threadIdx.x;
    int e = gid >> 5;
    int u = gid & 31;
    if (e >= n_edges) return;
    const int r = rows[e];
    const int c = cols[e];
    const float* Xr = X + (size_t)c * 128;
    const float x0 = Xr[u];
    const float x1a = Xr[32 + 3 * u], x1b = Xr[33 + 3 * u], x1c = Xr[34 + 3 * u];
    const float* Ye = Y + (size_t)e * 4;
    const float y0 = Ye[0], y1a = Ye[1], y1b = Ye[2], y1c = Ye[3];
    const float* We = W + (size_t)e * 160;
    const float w0 = We[u], w1 = We[32 + u], w2 = We[64 + u], w3 = We[96 + u], w4 = We[128 + u];
    const float w1x0 = w1 * x0;
    const float w2y0 = w2 * y0;
    const float dot = x1a * y1a + x1b * y1b + x1c * y1c;
    const float w4s = w4 * SQRT2_INV;
    float* Zr = Z + (size_t)r * 352;
    atomicAdd(&Zr[u], w0 * x0 * y0);
    atomicAdd(&Zr[32 + 3 * u + 0], w1x0 * y1a);
    atomicAdd(&Zr[32 + 3 * u + 1], w1x0 * y1b);
    atomicAdd(&Zr[32 + 3 * u + 2], w1x0 * y1c);
    atomicAdd(&Zr[128 + 3 * u + 0], w2y0 * x1a);
    atomicAdd(&Zr[128 + 3 * u + 1], w2y0 * x1b);
    atomicAdd(&Zr[128 + 3 * u + 2], w2y0 * x1c);
    atomicAdd(&Zr[224 + u], w3 * dot * SQRT3_INV);
    atomicAdd(&Zr[256 + 3 * u + 0], w4s * (x1b * y1c - x1c * y1b));
    atomicAdd(&Zr[256 + 3 * u + 1], w4s * (x1c * y1a - x1a * y1c));
    atomicAdd(&Zr[256 + 3 * u + 2], w4s * (x1a * y1b - x1b * y1a));
}

extern "C" void kernel_launch(void* const* d_in, const int* in_sizes, int n_in,
                              void* d_out, int out_size, void* d_ws, size_t ws_size,
                              hipStream_t stream) {
    const float* X    = (const float*)d_in[0];
    const float* Y    = (const float*)d_in[1];
    const float* W    = (const float*)d_in[2];
    const int*   rows = (const int*)d_in[3];
    const int*   cols = (const int*)d_in[4];
    float* Z = (float*)d_out;

    const int n_edges = in_sizes[3];
    const int n_nodes = in_sizes[0] / 128;

    // ws layout: slots i2[n_nodes*KCAP] | cnt[n_nodes+1] (last = ovf_cnt) | ovf_list[n_edges]
    size_t slots_bytes = (size_t)n_nodes * KCAP * sizeof(i2);
    size_t need = slots_bytes + (size_t)(n_nodes + 1 + n_edges) * sizeof(int);
    if (ws_size < need) {
        hipMemsetAsync(d_out, 0, (size_t)out_size * sizeof(float), stream);
        const long long threads_total = (long long)n_edges * 32;
        const int grid = (int)((threads_total + 255) / 256);
        tpc_edge_kernel<<<grid, 256, 0, stream>>>(X, Y, W, rows, cols, Z, n_edges);
        return;
    }

    char* base = (char*)d_ws;
    i2*  slots    = (i2*)base;
    int* cnt      = (int*)(base + slots_bytes);   // n_nodes+1, last = ovf counter
    int* ovf_list = cnt + n_nodes + 1;

    hipMemsetAsync(cnt, 0, (size_t)(n_nodes + 1) * sizeof(int), stream);

    const int nQuads = (n_edges + 3) / 4;
    const int gE = (nQuads + 255) / 256;
    scatter_bin_kernel<<<gE, 256, 0, stream>>>(rows, cols, cnt, slots, ovf_list, n_nodes, n_edges);

    // one full wave per node, 4 nodes per 256-thread block; handles overflow itself
    const int gG = (n_nodes + 3) / 4;
    tpc_gather<<<gG, 256, 0, stream>>>(X, Y, W, rows, cols, slots, cnt, ovf_list, Z, n_nodes);
}

// Round 14
// 133.612 us; speedup vs baseline: 1.0847x; 1.0847x over previous
//
#include <hip/hip_runtime.h>

// TensorProductConv: Z[rows[e]] += msg(X[cols[e]], Y[e], W[e]),  msg is 352 f32.
// Inputs: X (N,128) f32, Y (E,4) f32, W (E,160) f32, rows (E) int32, cols (E) int32
// Output: Z (N, 352) f32.
//
// FINAL (R12 config, 134.3 us): memset(cnt) -> scatter_bin (KCAP=64
// fixed-capacity bins, {e,col} i2 records, 2 edges/thread) -> tpc_gather
// (one full 64-lane wave per node, even/odd slot split, __shfl_xor(32)
// combine, x2 unroll per slot; overflowed nodes scan ovf_list themselves --
// zero cost when no overflow, race-free since the owning wave accumulates
// before its single store).
// R13's 4-edge/thread + nontemporal slot writes regressed (+10.6 us) — the
// L2 absorbs random 8 B slot writes better without cache hints.

#define SQRT3_INV 0.57735026918962576451f
#define SQRT2_INV 0.70710678118654752440f
#define KCAP 64

typedef __attribute__((ext_vector_type(4))) float f4;
typedef __attribute__((ext_vector_type(2))) int   i2;
struct F3 { float a, b, c; };   // 12 B -> global_load_dwordx3

#define EDGE_BODY(E_, C_)                                                     \
    do {                                                                      \
        const float* We = W + (size_t)(unsigned)(E_) * 160;                   \
        const float* Xr = X + (size_t)(unsigned)(C_) * 128;                   \
        const f4 yv = *reinterpret_cast<const f4*>(Y + (size_t)(unsigned)(E_) * 4); \
        const float x0 = Xr[u];                                               \
        const F3 x1 = *reinterpret_cast<const F3*>(Xr + 32 + 3 * u);          \
        const float x1a = x1.a, x1b = x1.b, x1c = x1.c;                       \
        const float y0 = yv.x, y1a = yv.y, y1b = yv.z, y1c = yv.w;            \
        const float w0 = __builtin_nontemporal_load(We + u);                  \
        const float w1 = __builtin_nontemporal_load(We + 32 + u);             \
        const float w2 = __builtin_nontemporal_load(We + 64 + u);             \
        const float w3 = __builtin_nontemporal_load(We + 96 + u);             \
        const float w4 = __builtin_nontemporal_load(We + 128 + u);            \
        a1 += w0 * x0 * y0;                                                   \
        const float w1x0 = w1 * x0;                                           \
        a2a += w1x0 * y1a; a2b += w1x0 * y1b; a2c += w1x0 * y1c;              \
        const float w2y0 = w2 * y0;                                           \
        a3a += w2y0 * x1a; a3b += w2y0 * x1b; a3c += w2y0 * x1c;              \
        const float dot = x1a * y1a + x1b * y1b + x1c * y1c;                  \
        a4 += w3 * dot * SQRT3_INV;                                           \
        const float w4s = w4 * SQRT2_INV;                                     \
        a5a += w4s * (x1b * y1c - x1c * y1b);                                 \
        a5b += w4s * (x1c * y1a - x1a * y1c);                                 \
        a5c += w4s * (x1a * y1b - x1b * y1a);                                 \
    } while (0)

// ---------- build: bin edges by destination row, 2 edges per thread ----------
__global__ void scatter_bin_kernel(const int* __restrict__ rows, const int* __restrict__ cols,
                                   int* __restrict__ cnt, i2* __restrict__ slots,
                                   int* __restrict__ ovf_list, int n_nodes, int nE) {
    int t = blockIdx.x * blockDim.x + threadIdx.x;
    int e0 = t * 2;
    if (e0 >= nE) return;
    if (e0 + 1 < nE) {
        const i2 rr = *reinterpret_cast<const i2*>(rows + e0);
        const i2 cc = *reinterpret_cast<const i2*>(cols + e0);
        int p0 = atomicAdd(&cnt[rr.x], 1);
        int p1 = atomicAdd(&cnt[rr.y], 1);
        if (p0 < KCAP) {
            i2 rec; rec.x = e0; rec.y = cc.x;
            slots[(size_t)rr.x * KCAP + p0] = rec;
        } else {
            int q = atomicAdd(&cnt[n_nodes], 1);
            ovf_list[q] = e0;
        }
        if (p1 < KCAP) {
            i2 rec; rec.x = e0 + 1; rec.y = cc.y;
            slots[(size_t)rr.y * KCAP + p1] = rec;
        } else {
            int q = atomicAdd(&cnt[n_nodes], 1);
            ovf_list[q] = e0 + 1;
        }
    } else {
        int r = rows[e0];
        int p = atomicAdd(&cnt[r], 1);
        if (p < KCAP) {
            i2 rec; rec.x = e0; rec.y = cols[e0];
            slots[(size_t)r * KCAP + p] = rec;
        } else {
            int q = atomicAdd(&cnt[n_nodes], 1);
            ovf_list[q] = e0;
        }
    }
}

// ---------- main gather: one node per full 64-lane wave, slot-split ----------
__global__ __launch_bounds__(256) void tpc_gather(
    const float* __restrict__ X,
    const float* __restrict__ Y,
    const float* __restrict__ W,
    const int* __restrict__ rows,
    const int* __restrict__ cols,
    const i2* __restrict__ slots,
    const int* __restrict__ cnt,
    const int* __restrict__ ovf_list,
    float* __restrict__ Z,
    int n_nodes)
{
    int node = blockIdx.x * 4 + (threadIdx.x >> 6);   // 4 waves per 256-thr block
    if (node >= n_nodes) return;
    const int lane = threadIdx.x & 63;
    const int u    = lane & 31;     // channel
    const int slot = lane >> 5;     // 0: even edges, 1: odd edges

    float a1 = 0.f, a2a = 0.f, a2b = 0.f, a2c = 0.f;
    float a3a = 0.f, a3b = 0.f, a3c = 0.f, a4 = 0.f;
    float a5a = 0.f, a5b = 0.f, a5c = 0.f;

    const int ncnt = cnt[node];
    int n = ncnt > KCAP ? KCAP : ncnt;
    const i2* sb = slots + (size_t)node * KCAP;

    int i = 0;
    for (; i + 3 < n; i += 4) {
        // 2 edges per slot in flight (4 per wave)
        const i2 ec0 = sb[i + slot];
        const i2 ec1 = sb[i + 2 + slot];
        EDGE_BODY(ec0.x, ec0.y);
        EDGE_BODY(ec1.x, ec1.y);
    }
    for (; i + slot < n; i += 2) {
        const i2 ec0 = sb[i + slot];
        EDGE_BODY(ec0.x, ec0.y);
    }

    // overflow (never in practice): the owning wave handles its own edges,
    // race-free because it happens before this wave's single Z store.
    if (ncnt > KCAP) {
        const int tot = cnt[n_nodes];
        for (int j = slot; j < tot; j += 2) {
            const int e = ovf_list[j];
            if (rows[e] == node) {
                const int c = cols[e];
                EDGE_BODY(e, c);
            }
        }
    }

    // combine slot halves (lane <-> lane^32)
    a1  += __shfl_xor(a1,  32, 64);
    a2a += __shfl_xor(a2a, 32, 64);
    a2b += __shfl_xor(a2b, 32, 64);
    a2c += __shfl_xor(a2c, 32, 64);
    a3a += __shfl_xor(a3a, 32, 64);
    a3b += __shfl_xor(a3b, 32, 64);
    a3c += __shfl_xor(a3c, 32, 64);
    a4  += __shfl_xor(a4,  32, 64);
    a5a += __shfl_xor(a5a, 32, 64);
    a5b += __shfl_xor(a5b, 32, 64);
    a5c += __shfl_xor(a5c, 32, 64);

    if (slot == 0) {
        float* Zr = Z + (size_t)node * 352;
        __builtin_nontemporal_store(a1,  Zr + u);
        __builtin_nontemporal_store(a2a, Zr + 32 + 3 * u + 0);
        __builtin_nontemporal_store(a2b, Zr + 32 + 3 * u + 1);
        __builtin_nontemporal_store(a2c, Zr + 32 + 3 * u + 2);
        __builtin_nontemporal_store(a3a, Zr + 128 + 3 * u + 0);
        __builtin_nontemporal_store(a3b, Zr + 128 + 3 * u + 1);
        __builtin_nontemporal_store(a3c, Zr + 128 + 3 * u + 2);
        __builtin_nontemporal_store(a4,  Zr + 224 + u);
        __builtin_nontemporal_store(a5a, Zr + 256 + 3 * u + 0);
        __builtin_nontemporal_store(a5b, Zr + 256 + 3 * u + 1);
        __builtin_nontemporal_store(a5c, Zr + 256 + 3 * u + 2);
    }
}

// ---------- last-resort fallback (atomic scatter) if ws too small ----------
__global__ __launch_bounds__(256) void tpc_edge_kernel(
    const float* __restrict__ X, const float* __restrict__ Y, const float* __restrict__ W,
    const int* __restrict__ rows, const int* __restrict__ cols, float* __restrict__ Z, int n_edges)
{
    int gid = blockIdx.x * blockDim.x + threadIdx.x;
    int e = gid >> 5;
    int u = gid & 31;
    if (e >= n_edges) return;
    const int r = rows[e];
    const int c = cols[e];
    const float* Xr = X + (size_t)c * 128;
    const float x0 = Xr[u];
    const float x1a = Xr[32 + 3 * u], x1b = Xr[33 + 3 * u], x1c = Xr[34 + 3 * u];
    const float* Ye = Y + (size_t)e * 4;
    const float y0 = Ye[0], y1a = Ye[1], y1b = Ye[2], y1c = Ye[3];
    const float* We = W + (size_t)e * 160;
    const float w0 = We[u], w1 = We[32 + u], w2 = We[64 + u], w3 = We[96 + u], w4 = We[128 + u];
    const float w1x0 = w1 * x0;
    const float w2y0 = w2 * y0;
    const float dot = x1a * y1a + x1b * y1b + x1c * y1c;
    const float w4s = w4 * SQRT2_INV;
    float* Zr = Z + (size_t)r * 352;
    atomicAdd(&Zr[u], w0 * x0 * y0);
    atomicAdd(&Zr[32 + 3 * u + 0], w1x0 * y1a);
    atomicAdd(&Zr[32 + 3 * u + 1], w1x0 * y1b);
    atomicAdd(&Zr[32 + 3 * u + 2], w1x0 * y1c);
    atomicAdd(&Zr[128 + 3 * u + 0], w2y0 * x1a);
    atomicAdd(&Zr[128 + 3 * u + 1], w2y0 * x1b);
    atomicAdd(&Zr[128 + 3 * u + 2], w2y0 * x1c);
    atomicAdd(&Zr[224 + u], w3 * dot * SQRT3_INV);
    atomicAdd(&Zr[256 + 3 * u + 0], w4s * (x1b * y1c - x1c * y1b));
    atomicAdd(&Zr[256 + 3 * u + 1], w4s * (x1c * y1a - x1a * y1c));
    atomicAdd(&Zr[256 + 3 * u + 2], w4s * (x1a * y1b - x1b * y1a));
}

extern "C" void kernel_launch(void* const* d_in, const int* in_sizes, int n_in,
                              void* d_out, int out_size, void* d_ws, size_t ws_size,
                              hipStream_t stream) {
    const float* X    = (const float*)d_in[0];
    const float* Y    = (const float*)d_in[1];
    const float* W    = (const float*)d_in[2];
    const int*   rows = (const int*)d_in[3];
    const int*   cols = (const int*)d_in[4];
    float* Z = (float*)d_out;

    const int n_edges = in_sizes[3];
    const int n_nodes = in_sizes[0] / 128;

    // ws layout: slots i2[n_nodes*KCAP] | cnt[n_nodes+1] (last = ovf_cnt) | ovf_list[n_edges]
    size_t slots_bytes = (size_t)n_nodes * KCAP * sizeof(i2);
    size_t need = slots_bytes + (size_t)(n_nodes + 1 + n_edges) * sizeof(int);
    if (ws_size < need) {
        hipMemsetAsync(d_out, 0, (size_t)out_size * sizeof(float), stream);
        const long long threads_total = (long long)n_edges * 32;
        const int grid = (int)((threads_total + 255) / 256);
        tpc_edge_kernel<<<grid, 256, 0, stream>>>(X, Y, W, rows, cols, Z, n_edges);
        return;
    }

    char* base = (char*)d_ws;
    i2*  slots    = (i2*)base;
    int* cnt      = (int*)(base + slots_bytes);   // n_nodes+1, last = ovf counter
    int* ovf_list = cnt + n_nodes + 1;

    hipMemsetAsync(cnt, 0, (size_t)(n_nodes + 1) * sizeof(int), stream);

    const int nPairs = (n_edges + 1) / 2;
    const int gE = (nPairs + 255) / 256;
    scatter_bin_kernel<<<gE, 256, 0, stream>>>(rows, cols, cnt, slots, ovf_list, n_nodes, n_edges);

    // one full wave per node, 4 nodes per 256-thread block; handles overflow itself
    const int gG = (n_nodes + 3) / 4;
    tpc_gather<<<gG, 256, 0, stream>>>(X, Y, W, rows, cols, slots, cnt, ovf_list, Z, n_nodes);
}